// Round 16
// baseline (66.731 us; speedup 1.0000x reference)
//
#include <hip/hip_runtime.h>
#include <math.h>

#define ALPHA 5e-4f
#define BIG 1e30f

typedef __attribute__((ext_vector_type(4))) float f32x4;

__device__ __forceinline__ void gload16(const void* g, void* l) {
    __builtin_amdgcn_global_load_lds(
        (const __attribute__((address_space(1))) void*)g,
        (__attribute__((address_space(3))) void*)l, 16, 0, 0);
}

// ---------------- Kernel A: f32 -> fp8(e4m3) convert + exact f32 row norms ----------------
// sqn32 = ||x_row||^2 of ORIGINAL f32 values (bias-free metric; R9-verified).
__global__ __launch_bounds__(256)
void conv_fp8_kernel(const float* __restrict__ X, unsigned char* __restrict__ Xq,
                     float* __restrict__ sqn32, int d) {
    const int w = threadIdx.x >> 6, lane = threadIdx.x & 63;
    const int row = blockIdx.x * 4 + w;
    const float4* src = reinterpret_cast<const float4*>(X + (size_t)row * d);
    int4* dst = reinterpret_cast<int4*>(Xq + (size_t)row * d);
    float s = 0.f;
    const int ng = d >> 4;                 // 16 floats / group
    for (int g = lane; g < ng; g += 64) {
        int wds[4];
#pragma unroll
        for (int q = 0; q < 4; ++q) {
            float4 v = src[g * 4 + q];
            s += v.x * v.x + v.y * v.y + v.z * v.z + v.w * v.w;
            int t0 = __builtin_amdgcn_cvt_pk_fp8_f32(v.x, v.y, 0, false);
            wds[q] = __builtin_amdgcn_cvt_pk_fp8_f32(v.z, v.w, t0, true);
        }
        dst[g] = make_int4(wds[0], wds[1], wds[2], wds[3]);
    }
    for (int off = 1; off < 64; off <<= 1) s += __shfl_xor(s, off, 64);
    if (lane == 0) sqn32[row] = s;
}

// ---------------- Kernel B: fp8 gram, 256^2 tiles, phase-split counted-vmcnt ----------------
// R16: m201-template port.  Full square grid 16x16 = 256 blocks (1 block/CU,
// zero tail).  512 threads = 8 waves (2M x 4N); per-wave output 128x64 =
// acc[8][4].  K-tile = 64 B (16 tiles), 4-deep LDS ring (4 x (16KB A + 16KB B)
// = 128 KB), staging runs 3 tiles ahead, 2 gload16/thread/phase.
// Per tile: 2 phases, each {12 ds_read_b64 || 2 gload16 -> s_barrier ->
// setprio(1) -> 32 MFMA -> setprio(0) -> s_barrier}; vmcnt(8) ONLY at tile
// boundaries (2 tiles = 8 loads stay in flight; never drained mid-loop).
// This is the documented escape (T3+T4+T5) from the ~1650cyc/block-step
// 2-barrier ceiling that R5/R15 sat on (m233/m218).
// Swizzle (R9-verified, 64B rows): stored 16B-block b of row r holds global
// block b ^ ((r>>1)&3); source block = (l&3)^((l>>3)&3); read 8B-chunk
// ch = (ww*4+lg) ^ (((lc>>1)&3)<<1)  -> b64 bandwidth-floor access.
// Selection value s = sqn32[col] - 2*<xq_i,xq_j>  (bias-free metric).
// Row-path only: slot = cb*4 + wcn -> exactly 64 slots/row.
#define BMQ 256
#define TKB 64

__global__ __launch_bounds__(512)
void gram_top2_mfma(const unsigned char* __restrict__ Xq, const float* __restrict__ sqn,
                    float* __restrict__ cand_s, int* __restrict__ cand_i,
                    int n, int d, int nbc, int cpx) {
    __shared__ unsigned char As[4][BMQ * TKB];   // 4 x 16 KB
    __shared__ unsigned char Bs[4][BMQ * TKB];   // 4 x 16 KB

    // XCD chunking: 32 consecutive tiles per XCD -> rb in [x*2, x*2+2)
    const int bid = blockIdx.x;
    const int swz = (bid & 7) * cpx + (bid >> 3);
    const int rb = swz >> 4, cb = swz & 15;      // nbc = 16

    const int row0 = rb * BMQ, col0 = cb * BMQ;
    const int t = threadIdx.x;
    const int w = t >> 6, l = t & 63;
    const int wr = w >> 2, wcn = w & 3;          // 2M x 4N wave grid
    const int lc = l & 15, lg = l >> 4;

    f32x4 acc[8][4];
#pragma unroll
    for (int i = 0; i < 8; ++i)
#pragma unroll
        for (int j = 0; j < 4; ++j) acc[i][j] = (f32x4){0.f, 0.f, 0.f, 0.f};

    // staging: wave w stages rows [w*16, w*16+16) and [128+w*16, ...).
    // lane l -> row w*16 + (l>>2), source 16B-block (l&3)^((l>>3)&3).
    const int srow = w * 16 + (l >> 2);
    const int sblk = ((l & 3) ^ ((l >> 3) & 3)) << 4;
    const size_t gA0 = (size_t)(row0 + srow) * d + sblk;
    const size_t gB0 = (size_t)(col0 + srow) * d + sblk;
    const size_t hstep = (size_t)128 * d;        // +128 rows
    const int wb = w * 1024;                     // LDS dest base (1 KB / wave / instr)

    const int nt = d / TKB;                      // 16 K-tiles

    // stage macros: 2 gload16 each (A halves or B halves of tile ks)
#define STAGE_A(bi, ks)                                                   \
    {                                                                     \
        const size_t ko = (size_t)(ks) * TKB;                             \
        gload16(Xq + gA0 + ko, As[bi] + wb);                              \
        gload16(Xq + gA0 + ko + hstep, As[bi] + wb + 8192);               \
    }
#define STAGE_B(bi, ks)                                                   \
    {                                                                     \
        const size_t ko = (size_t)(ks) * TKB;                             \
        gload16(Xq + gB0 + ko, Bs[bi] + wb);                              \
        gload16(Xq + gB0 + ko + hstep, Bs[bi] + wb + 8192);               \
    }

    // prologue: tiles 0,1,2 in flight (12 loads/thread)
    STAGE_A(0, 0) STAGE_B(0, 0)
    STAGE_A(1, 1) STAGE_B(1, 1)
    STAGE_A(2, 2) STAGE_B(2, 2)
    asm volatile("s_waitcnt vmcnt(8)" ::: "memory");   // tile 0 landed
    __builtin_amdgcn_s_barrier();

    const int csw = ((lc >> 1) & 3) << 1;        // read-side chunk XOR (uniform/lane)

    for (int ks = 0; ks < nt; ++ks) {
        const int bi = ks & 3;
        const int sb = (ks + 3) & 3;
        const bool st = (ks + 3) < nt;

#pragma unroll
        for (int ww = 0; ww < 2; ++ww) {
            // ---- ds-load frags for window ww ----
            long long a[8], b[4];
            const int ch = ((ww * 4 + lg) ^ csw) * 8;
#pragma unroll
            for (int mi = 0; mi < 8; ++mi)
                a[mi] = *reinterpret_cast<const long long*>(
                    &As[bi][(wr * 128 + mi * 16 + lc) * TKB + ch]);
#pragma unroll
            for (int ni = 0; ni < 4; ++ni)
                b[ni] = *reinterpret_cast<const long long*>(
                    &Bs[bi][(wcn * 64 + ni * 16 + lc) * TKB + ch]);

            // ---- stage half of tile ks+3 ----
            if (st) {
                if (ww == 0) { STAGE_A(sb, ks + 3) }
                else         { STAGE_B(sb, ks + 3) }
            }
            __builtin_amdgcn_s_barrier();

            __builtin_amdgcn_s_setprio(1);
#pragma unroll
            for (int mi = 0; mi < 8; ++mi)
#pragma unroll
                for (int ni = 0; ni < 4; ++ni)
                    acc[mi][ni] = __builtin_amdgcn_mfma_f32_16x16x32_fp8_fp8(
                        a[mi], b[ni], acc[mi][ni], 0, 0, 0);
            __builtin_amdgcn_s_setprio(0);

            if (ww == 1) {
                // end of tile: ensure tile ks+1 landed before next phase reads it
                if (ks <= nt - 4) {
                    asm volatile("s_waitcnt vmcnt(8)" ::: "memory");
                } else if (ks == nt - 3) {
                    asm volatile("s_waitcnt vmcnt(4)" ::: "memory");
                } else if (ks == nt - 2) {
                    asm volatile("s_waitcnt vmcnt(0)" ::: "memory");
                }
            }
            __builtin_amdgcn_s_barrier();
        }
    }
#undef STAGE_A
#undef STAGE_B

    // ---- row-path epilogue: per-row top-2 over this wave's 64-col strip ----
    // C frag layout: col = lane&15, row = (lane>>4)*4 + reg.
    float sq_c[4];
#pragma unroll
    for (int ni = 0; ni < 4; ++ni) sq_c[ni] = sqn[col0 + wcn * 64 + ni * 16 + lc];
    const int strip_r = cb * 4 + wcn;

#pragma unroll
    for (int mi = 0; mi < 8; ++mi) {
#pragma unroll
        for (int j = 0; j < 4; ++j) {
            const int grow = row0 + wr * 128 + mi * 16 + lg * 4 + j;
            float s1v = BIG, s2v = BIG;
            int i1 = -1, i2 = -1;
#pragma unroll
            for (int ni = 0; ni < 4; ++ni) {
                const int gcol = col0 + wcn * 64 + ni * 16 + lc;
                float s = sq_c[ni] - 2.f * acc[mi][ni][j];
                if (gcol == grow) s = BIG;   // exclude self (diag blocks)
                if (s < s1v) { s2v = s1v; i2 = i1; s1v = s; i1 = gcol; }
                else if (s < s2v) { s2v = s; i2 = gcol; }
            }
            for (int off = 1; off < 16; off <<= 1) {
                float b1 = __shfl_xor(s1v, off, 16);
                int  bi1 = __shfl_xor(i1, off, 16);
                float b2 = __shfl_xor(s2v, off, 16);
                int  bi2 = __shfl_xor(i2, off, 16);
                if (b1 < s1v) { s2v = s1v; i2 = i1; s1v = b1; i1 = bi1; }
                else if (b1 < s2v) { s2v = b1; i2 = bi1; }
                if (b2 < s2v) { s2v = b2; i2 = bi2; }
            }
            if (lc == 0) {
                size_t base = ((size_t)grow * 64 + strip_r) * 2;
                cand_s[base] = s1v; cand_s[base + 1] = s2v;
                cand_i[base] = i1; cand_i[base + 1] = i2;
            }
        }
    }
}

// ---------------- Kernel C: merge 128 candidates/row + edge terms ----------------
__global__ __launch_bounds__(256)
void merge_edges_kernel(const float* __restrict__ sqn,
                        const float* __restrict__ cand_s, const int* __restrict__ cand_i,
                        const int* __restrict__ yb, const float* __restrict__ yo,
                        float* __restrict__ partial, int ncls) {
    const int w = threadIdx.x >> 6, lane = threadIdx.x & 63;
    const int row = blockIdx.x * 4 + w;

    float2 cs = reinterpret_cast<const float2*>(cand_s + (size_t)row * 128)[lane];
    int2   ci = reinterpret_cast<const int2*>(cand_i + (size_t)row * 128)[lane];
    float s1 = cs.x, s2 = cs.y;
    int i1 = ci.x, i2 = ci.y;
    if (s2 < s1) { float ts = s1; s1 = s2; s2 = ts; int ti = i1; i1 = i2; i2 = ti; }

    for (int off = 1; off < 64; off <<= 1) {
        float b1 = __shfl_xor(s1, off, 64);
        int  bi1 = __shfl_xor(i1, off, 64);
        float b2 = __shfl_xor(s2, off, 64);
        int  bi2 = __shfl_xor(i2, off, 64);
        if (b1 < s1) { s2 = s1; i2 = i1; s1 = b1; i1 = bi1; }
        else if (b1 < s2) { s2 = b1; i2 = bi1; }
        if (b2 < s2) { s2 = b2; i2 = bi2; }
    }
    const int yr = yb[row];
    const float sr = sqn[row];
    float w1 = ((yr == yb[i1]) ? 1.f : -1.f) * expf(-sqrtf(fmaxf(sr + s1, 0.f)));
    float w2 = ((yr == yb[i2]) ? 1.f : -1.f) * expf(-sqrtf(fmaxf(sr + s2, 0.f)));

    const float4* yr4 = reinterpret_cast<const float4*>(yo + (size_t)row * ncls);
    const float4* y14 = reinterpret_cast<const float4*>(yo + (size_t)i1 * ncls);
    const float4* y24 = reinterpret_cast<const float4*>(yo + (size_t)i2 * ncls);
    const int nv4 = ncls >> 2;             // 250
    float a1 = 0.f, a2 = 0.f;
    for (int c = lane; c < nv4; c += 64) {
        float4 v = yr4[c];
        float4 u1 = y14[c];
        float4 u2 = y24[c];
        float tx = v.x - u1.x, ty = v.y - u1.y, tz = v.z - u1.z, tw = v.w - u1.w;
        a1 = fmaf(tx, tx, fmaf(ty, ty, fmaf(tz, tz, fmaf(tw, tw, a1))));
        tx = v.x - u2.x; ty = v.y - u2.y; tz = v.z - u2.z; tw = v.w - u2.w;
        a2 = fmaf(tx, tx, fmaf(ty, ty, fmaf(tz, tz, fmaf(tw, tw, a2))));
    }
    for (int c = (nv4 << 2) + lane; c < ncls; c += 64) {   // tail (empty for 1000)
        float v = yo[(size_t)row * ncls + c];
        float t1 = v - yo[(size_t)i1 * ncls + c];
        float t2 = v - yo[(size_t)i2 * ncls + c];
        a1 = fmaf(t1, t1, a1);
        a2 = fmaf(t2, t2, a2);
    }
    for (int off = 1; off < 64; off <<= 1) {
        a1 += __shfl_xor(a1, off, 64);
        a2 += __shfl_xor(a2, off, 64);
    }
    if (lane == 0)
        partial[row] = w1 * sqrtf(a1) + w2 * sqrtf(a2);
}

// ---------------- Kernel D: final reduction of n partials ----------------
__global__ __launch_bounds__(256)
void final_reduce_kernel(const float* __restrict__ partial, float* __restrict__ out, int n) {
    const int t = threadIdx.x;
    __shared__ float red[4];
    float s = 0.f;
    const int nv4 = n >> 2;
    const float4* p4 = reinterpret_cast<const float4*>(partial);
    for (int c = t; c < nv4; c += 256) {
        float4 v = p4[c];
        s += v.x + v.y + v.z + v.w;
    }
    for (int off = 1; off < 64; off <<= 1) s += __shfl_xor(s, off, 64);
    if ((t & 63) == 0) red[t >> 6] = s;
    __syncthreads();
    if (t == 0) out[0] = ALPHA * (red[0] + red[1] + red[2] + red[3]);
}

extern "C" void kernel_launch(void* const* d_in, const int* in_sizes, int n_in,
                              void* d_out, int out_size, void* d_ws, size_t ws_size,
                              hipStream_t stream) {
    const float* X  = (const float*)d_in[0];
    const int*   yb = (const int*)d_in[1];
    const float* yo = (const float*)d_in[2];
    float* out = (float*)d_out;

    const int n    = in_sizes[1];          // 4096
    const int d    = in_sizes[0] / n;      // 1024
    const int ncls = in_sizes[2] / n;      // 1000
    const int nbc  = n / BMQ;              // 16

    // workspace: sqn32 | Xq (fp8) | cand_s | cand_i | partial
    char* wsb = (char*)d_ws;
    size_t off = 0;
    float* sqn32 = (float*)(wsb + off);         off += ((size_t)n * 4 + 255) & ~(size_t)255;
    unsigned char* Xq = (unsigned char*)(wsb + off); off += ((size_t)n * d + 255) & ~(size_t)255;
    float* cand_s = (float*)(wsb + off);        off += ((size_t)n * 64 * 2 * 4 + 255) & ~(size_t)255;
    int*   cand_i = (int*)(wsb + off);          off += ((size_t)n * 64 * 2 * 4 + 255) & ~(size_t)255;
    float* partial = (float*)(wsb + off);

    conv_fp8_kernel<<<n / 4, 256, 0, stream>>>(X, Xq, sqn32, d);

    const int nsq = nbc * nbc;             // 256 = 32*8 -> 1 block/CU, zero tail
    const int cpx = nsq / 8;               // 32
    gram_top2_mfma<<<nsq, 512, 0, stream>>>(Xq, sqn32, cand_s, cand_i, n, d, nbc, cpx);

    merge_edges_kernel<<<n / 4, 256, 0, stream>>>(sqn32, cand_s, cand_i, yb, yo, partial, ncls);

    final_reduce_kernel<<<1, 256, 0, stream>>>(partial, out, n);
}

// Round 17
// 62.515 us; speedup vs baseline: 1.0674x; 1.0674x over previous
//
#include <hip/hip_runtime.h>
#include <math.h>

#define ALPHA 5e-4f
#define BIG 1e30f

typedef __attribute__((ext_vector_type(4))) float f32x4;
typedef __attribute__((ext_vector_type(2))) long long llx2;

__device__ __forceinline__ void gload16(const void* g, void* l) {
    __builtin_amdgcn_global_load_lds(
        (const __attribute__((address_space(1))) void*)g,
        (__attribute__((address_space(3))) void*)l, 16, 0, 0);
}

// ---------------- Kernel A: f32 -> fp8(e4m3) convert + exact f32 row norms ----------------
// sqn32 = ||x_row||^2 of ORIGINAL f32 values (bias-free metric; R9-verified).
__global__ __launch_bounds__(256)
void conv_fp8_kernel(const float* __restrict__ X, unsigned char* __restrict__ Xq,
                     float* __restrict__ sqn32, int d) {
    const int w = threadIdx.x >> 6, lane = threadIdx.x & 63;
    const int row = blockIdx.x * 4 + w;
    const float4* src = reinterpret_cast<const float4*>(X + (size_t)row * d);
    int4* dst = reinterpret_cast<int4*>(Xq + (size_t)row * d);
    float s = 0.f;
    const int ng = d >> 4;                 // 16 floats / group
    for (int g = lane; g < ng; g += 64) {
        int wds[4];
#pragma unroll
        for (int q = 0; q < 4; ++q) {
            float4 v = src[g * 4 + q];
            s += v.x * v.x + v.y * v.y + v.z * v.z + v.w * v.w;
            int t0 = __builtin_amdgcn_cvt_pk_fp8_f32(v.x, v.y, 0, false);
            wds[q] = __builtin_amdgcn_cvt_pk_fp8_f32(v.z, v.w, t0, true);
        }
        dst[g] = make_int4(wds[0], wds[1], wds[2], wds[3]);
    }
    for (int off = 1; off < 64; off <<= 1) s += __shfl_xor(s, off, 64);
    if (lane == 0) sqn32[row] = s;
}

// ---------------- Kernel B: fp8 gram, 256^2, faithful 4-phase/tile schedule ----------------
// R17: m201-template, faithfully.  Grid 16x16 = 256 blocks (1/CU, no tail),
// 512 threads = 8 waves (2M x 4N), per-wave 128x64 = acc[8][4].
// K-PERMUTATION TRICK: dot products are invariant to K reordering, so lane
// (lc,lg) reads ONE ds_read_b128 = K-bytes [lg*16, lg*16+16) and feeds halves
// to the two kk-MFMAs; A and B use the same permutation -> exact gram, b128
// width, 16B-block XOR swizzle (2-way banks, free).
// Schedule: K-tile = 64 B (16 tiles), 3-tile LDS ring (96 KB), 4 phases/tile:
//   {ds_read (6 b128 at p=0 incl B-frags held in regs; else 2) || 1 gload16
//    staging half-tile p of tile ks+2 -> s_barrier -> setprio(1) -> 16 MFMA
//    -> setprio(0) -> [p==3: vmcnt(4)] -> s_barrier}
// vmcnt(4) at tile boundary only: tile ks+2's 4 loads stay in flight, tile
// ks+1 is landed (each wave waits its OWN loads, then barrier publishes).
// Ring safety: staging into r2 = ring[(ks+2)%3] only overwrites the buffer
// whose reads finished at tile ks-1's closing barrier.
// Swizzle (R9-verified): stored 16B-block b of row r holds global block
// b ^ ((r>>1)&3); source block = (t&3)^((t>>3)&3); read at lg ^ ((lc>>1)&3).
// Selection value s = sqn32[col] - 2*<xq_i,xq_j> (bias-free metric).
// Row-path only: slot = cb*4 + wcn -> exactly 64 slots/row.
#define BMQ 256
#define TKB 64

__global__ __launch_bounds__(512)
void gram_top2_mfma(const unsigned char* __restrict__ Xq, const float* __restrict__ sqn,
                    float* __restrict__ cand_s, int* __restrict__ cand_i,
                    int n, int d, int nbc, int cpx) {
    __shared__ unsigned char As[3][BMQ * TKB];   // 3 x 16 KB
    __shared__ unsigned char Bs[3][BMQ * TKB];   // 3 x 16 KB

    const int bid = blockIdx.x;
    const int swz = (bid & 7) * cpx + (bid >> 3);
    const int rb = swz >> 4, cb = swz & 15;      // nbc = 16

    const int row0 = rb * BMQ, col0 = cb * BMQ;
    const int t = threadIdx.x;
    const int w = t >> 6, l = t & 63;
    const int wr = w >> 2, wcn = w & 3;          // 2M x 4N wave grid
    const int lc = l & 15, lg = l >> 4;

    f32x4 acc[8][4];
#pragma unroll
    for (int i = 0; i < 8; ++i)
#pragma unroll
        for (int j = 0; j < 4; ++j) acc[i][j] = (f32x4){0.f, 0.f, 0.f, 0.f};

    // staging: thread t -> row t>>2 (0..127 within a 128-row half), stored
    // 16B-block t&3, pre-swizzled global block (t&3)^((t>>3)&3).
    const int sblk = ((t & 3) ^ ((t >> 3) & 3)) << 4;
    const size_t gA0 = (size_t)(row0 + (t >> 2)) * d + sblk;
    const size_t gB0 = (size_t)(col0 + (t >> 2)) * d + sblk;
    const size_t hstep = (size_t)128 * d;        // +128 rows (second half)
    const int wb = w * 1024;                     // wave-uniform LDS dest base

    const int nt = d / TKB;                      // 16 K-tiles
    const int rblk = (lg ^ ((lc >> 1) & 3)) << 4;   // read-side swizzled block

    // prologue: tiles 0 -> ring0, 1 -> ring1 (4 half-tiles each)
#pragma unroll
    for (int s = 0; s < 2; ++s) {
        const size_t ko = (size_t)s * TKB;
        gload16(Xq + gA0 + ko,         As[s] + wb);
        gload16(Xq + gA0 + ko + hstep, As[s] + 8192 + wb);
        gload16(Xq + gB0 + ko,         Bs[s] + wb);
        gload16(Xq + gB0 + ko + hstep, Bs[s] + 8192 + wb);
    }
    asm volatile("s_waitcnt vmcnt(4)" ::: "memory");   // tile 0 landed
    __builtin_amdgcn_s_barrier();

    int r0 = 0, r1 = 1, r2 = 2;
    for (int ks = 0; ks < nt; ++ks) {
        const unsigned char* Ab = As[r0];
        const unsigned char* Bb = Bs[r0];
        const bool st = (ks + 2) < nt;
        const size_t ko2 = (size_t)(ks + 2) * TKB;
        llx2 bf[4];

#pragma unroll
        for (int p = 0; p < 4; ++p) {
            // ---- ds-loads for this phase ----
            if (p == 0) {
#pragma unroll
                for (int ni = 0; ni < 4; ++ni)
                    bf[ni] = *reinterpret_cast<const llx2*>(
                        Bb + (wcn * 64 + ni * 16 + lc) * 64 + rblk);
            }
            llx2 af[2];
#pragma unroll
            for (int q = 0; q < 2; ++q)
                af[q] = *reinterpret_cast<const llx2*>(
                    Ab + (wr * 128 + (p * 2 + q) * 16 + lc) * 64 + rblk);

            // ---- stage half-tile p of tile ks+2 into ring r2 ----
            if (st) {
                if (p == 0)      gload16(Xq + gA0 + ko2,         As[r2] + wb);
                else if (p == 1) gload16(Xq + gA0 + ko2 + hstep, As[r2] + 8192 + wb);
                else if (p == 2) gload16(Xq + gB0 + ko2,         Bs[r2] + wb);
                else             gload16(Xq + gB0 + ko2 + hstep, Bs[r2] + 8192 + wb);
            }
            __builtin_amdgcn_s_barrier();

            __builtin_amdgcn_s_setprio(1);
#pragma unroll
            for (int q = 0; q < 2; ++q) {
                const int mi = p * 2 + q;
#pragma unroll
                for (int ni = 0; ni < 4; ++ni) {
                    acc[mi][ni] = __builtin_amdgcn_mfma_f32_16x16x32_fp8_fp8(
                        af[q].x, bf[ni].x, acc[mi][ni], 0, 0, 0);
                    acc[mi][ni] = __builtin_amdgcn_mfma_f32_16x16x32_fp8_fp8(
                        af[q].y, bf[ni].y, acc[mi][ni], 0, 0, 0);
                }
            }
            __builtin_amdgcn_s_setprio(0);

            if (p == 3) {                        // tile boundary: ks+1 must be landed
                if (st) { asm volatile("s_waitcnt vmcnt(4)" ::: "memory"); }
                else    { asm volatile("s_waitcnt vmcnt(0)" ::: "memory"); }
            }
            __builtin_amdgcn_s_barrier();
        }
        int tmp = r0; r0 = r1; r1 = r2; r2 = tmp;
    }

    // ---- row-path epilogue: per-row top-2 over this wave's 64-col strip ----
    // C frag layout: col = lane&15, row = (lane>>4)*4 + reg.
    float sq_c[4];
#pragma unroll
    for (int ni = 0; ni < 4; ++ni) sq_c[ni] = sqn[col0 + wcn * 64 + ni * 16 + lc];
    const int strip_r = cb * 4 + wcn;

#pragma unroll
    for (int mi = 0; mi < 8; ++mi) {
#pragma unroll
        for (int j = 0; j < 4; ++j) {
            const int grow = row0 + wr * 128 + mi * 16 + lg * 4 + j;
            float s1v = BIG, s2v = BIG;
            int i1 = -1, i2 = -1;
#pragma unroll
            for (int ni = 0; ni < 4; ++ni) {
                const int gcol = col0 + wcn * 64 + ni * 16 + lc;
                float s = sq_c[ni] - 2.f * acc[mi][ni][j];
                if (gcol == grow) s = BIG;   // exclude self (diag blocks)
                if (s < s1v) { s2v = s1v; i2 = i1; s1v = s; i1 = gcol; }
                else if (s < s2v) { s2v = s; i2 = gcol; }
            }
            for (int off = 1; off < 16; off <<= 1) {
                float b1 = __shfl_xor(s1v, off, 16);
                int  bi1 = __shfl_xor(i1, off, 16);
                float b2 = __shfl_xor(s2v, off, 16);
                int  bi2 = __shfl_xor(i2, off, 16);
                if (b1 < s1v) { s2v = s1v; i2 = i1; s1v = b1; i1 = bi1; }
                else if (b1 < s2v) { s2v = b1; i2 = bi1; }
                if (b2 < s2v) { s2v = b2; i2 = bi2; }
            }
            if (lc == 0) {
                size_t base = ((size_t)grow * 64 + strip_r) * 2;
                cand_s[base] = s1v; cand_s[base + 1] = s2v;
                cand_i[base] = i1; cand_i[base + 1] = i2;
            }
        }
    }
}

// ---------------- Kernel C: merge 128 candidates/row + edge terms ----------------
__global__ __launch_bounds__(256)
void merge_edges_kernel(const float* __restrict__ sqn,
                        const float* __restrict__ cand_s, const int* __restrict__ cand_i,
                        const int* __restrict__ yb, const float* __restrict__ yo,
                        float* __restrict__ partial, int ncls) {
    const int w = threadIdx.x >> 6, lane = threadIdx.x & 63;
    const int row = blockIdx.x * 4 + w;

    float2 cs = reinterpret_cast<const float2*>(cand_s + (size_t)row * 128)[lane];
    int2   ci = reinterpret_cast<const int2*>(cand_i + (size_t)row * 128)[lane];
    float s1 = cs.x, s2 = cs.y;
    int i1 = ci.x, i2 = ci.y;
    if (s2 < s1) { float ts = s1; s1 = s2; s2 = ts; int ti = i1; i1 = i2; i2 = ti; }

    for (int off = 1; off < 64; off <<= 1) {
        float b1 = __shfl_xor(s1, off, 64);
        int  bi1 = __shfl_xor(i1, off, 64);
        float b2 = __shfl_xor(s2, off, 64);
        int  bi2 = __shfl_xor(i2, off, 64);
        if (b1 < s1) { s2 = s1; i2 = i1; s1 = b1; i1 = bi1; }
        else if (b1 < s2) { s2 = b1; i2 = bi1; }
        if (b2 < s2) { s2 = b2; i2 = bi2; }
    }
    const int yr = yb[row];
    const float sr = sqn[row];
    float w1 = ((yr == yb[i1]) ? 1.f : -1.f) * expf(-sqrtf(fmaxf(sr + s1, 0.f)));
    float w2 = ((yr == yb[i2]) ? 1.f : -1.f) * expf(-sqrtf(fmaxf(sr + s2, 0.f)));

    const float4* yr4 = reinterpret_cast<const float4*>(yo + (size_t)row * ncls);
    const float4* y14 = reinterpret_cast<const float4*>(yo + (size_t)i1 * ncls);
    const float4* y24 = reinterpret_cast<const float4*>(yo + (size_t)i2 * ncls);
    const int nv4 = ncls >> 2;             // 250
    float a1 = 0.f, a2 = 0.f;
    for (int c = lane; c < nv4; c += 64) {
        float4 v = yr4[c];
        float4 u1 = y14[c];
        float4 u2 = y24[c];
        float tx = v.x - u1.x, ty = v.y - u1.y, tz = v.z - u1.z, tw = v.w - u1.w;
        a1 = fmaf(tx, tx, fmaf(ty, ty, fmaf(tz, tz, fmaf(tw, tw, a1))));
        tx = v.x - u2.x; ty = v.y - u2.y; tz = v.z - u2.z; tw = v.w - u2.w;
        a2 = fmaf(tx, tx, fmaf(ty, ty, fmaf(tz, tz, fmaf(tw, tw, a2))));
    }
    for (int c = (nv4 << 2) + lane; c < ncls; c += 64) {   // tail (empty for 1000)
        float v = yo[(size_t)row * ncls + c];
        float t1 = v - yo[(size_t)i1 * ncls + c];
        float t2 = v - yo[(size_t)i2 * ncls + c];
        a1 = fmaf(t1, t1, a1);
        a2 = fmaf(t2, t2, a2);
    }
    for (int off = 1; off < 64; off <<= 1) {
        a1 += __shfl_xor(a1, off, 64);
        a2 += __shfl_xor(a2, off, 64);
    }
    if (lane == 0)
        partial[row] = w1 * sqrtf(a1) + w2 * sqrtf(a2);
}

// ---------------- Kernel D: final reduction of n partials ----------------
__global__ __launch_bounds__(256)
void final_reduce_kernel(const float* __restrict__ partial, float* __restrict__ out, int n) {
    const int t = threadIdx.x;
    __shared__ float red[4];
    float s = 0.f;
    const int nv4 = n >> 2;
    const float4* p4 = reinterpret_cast<const float4*>(partial);
    for (int c = t; c < nv4; c += 256) {
        float4 v = p4[c];
        s += v.x + v.y + v.z + v.w;
    }
    for (int off = 1; off < 64; off <<= 1) s += __shfl_xor(s, off, 64);
    if ((t & 63) == 0) red[t >> 6] = s;
    __syncthreads();
    if (t == 0) out[0] = ALPHA * (red[0] + red[1] + red[2] + red[3]);
}

extern "C" void kernel_launch(void* const* d_in, const int* in_sizes, int n_in,
                              void* d_out, int out_size, void* d_ws, size_t ws_size,
                              hipStream_t stream) {
    const float* X  = (const float*)d_in[0];
    const int*   yb = (const int*)d_in[1];
    const float* yo = (const float*)d_in[2];
    float* out = (float*)d_out;

    const int n    = in_sizes[1];          // 4096
    const int d    = in_sizes[0] / n;      // 1024
    const int ncls = in_sizes[2] / n;      // 1000
    const int nbc  = n / BMQ;              // 16

    // workspace: sqn32 | Xq (fp8) | cand_s | cand_i | partial
    char* wsb = (char*)d_ws;
    size_t off = 0;
    float* sqn32 = (float*)(wsb + off);         off += ((size_t)n * 4 + 255) & ~(size_t)255;
    unsigned char* Xq = (unsigned char*)(wsb + off); off += ((size_t)n * d + 255) & ~(size_t)255;
    float* cand_s = (float*)(wsb + off);        off += ((size_t)n * 64 * 2 * 4 + 255) & ~(size_t)255;
    int*   cand_i = (int*)(wsb + off);          off += ((size_t)n * 64 * 2 * 4 + 255) & ~(size_t)255;
    float* partial = (float*)(wsb + off);

    conv_fp8_kernel<<<n / 4, 256, 0, stream>>>(X, Xq, sqn32, d);

    const int nsq = nbc * nbc;             // 256 = 32*8 -> 1 block/CU, zero tail
    const int cpx = nsq / 8;               // 32
    gram_top2_mfma<<<nsq, 512, 0, stream>>>(Xq, sqn32, cand_s, cand_i, n, d, nbc, cpx);

    merge_edges_kernel<<<n / 4, 256, 0, stream>>>(sqn32, cand_s, cand_i, yb, yo, partial, ncls);

    final_reduce_kernel<<<1, 256, 0, stream>>>(partial, out, n);
}